// Round 9
// baseline (323.807 us; speedup 1.0000x reference)
//
#include <hip/hip_runtime.h>

typedef unsigned short u16;
typedef unsigned int   u32;
using bf16x8 = __attribute__((ext_vector_type(8))) __bf16;
using f32x4  = __attribute__((ext_vector_type(4))) float;
using u32x2  = __attribute__((ext_vector_type(2))) unsigned int;

__device__ __forceinline__ u16 f2b(float f){
  union { float f; u32 i; } v; v.f = f;
  u32 r = v.i + 0x7FFFu + ((v.i >> 16) & 1u);
  return (u16)(r >> 16);
}
__device__ __forceinline__ u32 pk_bf16_trunc(float a, float b){
  return __builtin_amdgcn_perm(__float_as_uint(b), __float_as_uint(a), 0x07060302u);
}

// ---------------------------------------------------------------- fused prelude:
// blocks [0,8192): LayerNorm row kernel; blocks [8192,12288): fp32->bf16 weight cvt.
__global__ __launch_bounds__(256) void pre_kernel(const float* __restrict__ x, const float* __restrict__ g,
                                                  const float* __restrict__ be, u16* __restrict__ h,
                                                  const float* __restrict__ s0, const float* __restrict__ s1,
                                                  const float* __restrict__ s2, const float* __restrict__ s3,
                                                  u16* __restrict__ wd){
  const int tid = threadIdx.x;
  if (blockIdx.x >= 8192){
    const int b2 = blockIdx.x - 8192;
    const float* srcs[4] = {s0, s1, s2, s3};
    const float* s = srcs[b2 >> 10];
    u16* dd = wd + (size_t)(b2 >> 10) * (1024u * 1024u);
    const int i = ((b2 & 1023) * 256 + tid) * 4;
    float4 v = *(const float4*)(s + i);
    uint2 o;
    o.x = (u32)f2b(v.x) | ((u32)f2b(v.y) << 16);
    o.y = (u32)f2b(v.z) | ((u32)f2b(v.w) << 16);
    *(uint2*)(dd + i) = o;
    return;
  }
  const int row = blockIdx.x;
  const float* xr = x + (size_t)row * 1024u;
  float4 raw = *(const float4*)(xr + tid * 4);
  float s  = raw.x + raw.y + raw.z + raw.w;
  float sq = raw.x*raw.x + raw.y*raw.y + raw.z*raw.z + raw.w*raw.w;
  #pragma unroll
  for (int m = 1; m < 64; m <<= 1){ s += __shfl_xor(s, m); sq += __shfl_xor(sq, m); }
  __shared__ float ws[4], wq[4];
  if ((tid & 63) == 0){ ws[tid >> 6] = s; wq[tid >> 6] = sq; }
  __syncthreads();
  s  = ws[0] + ws[1] + ws[2] + ws[3];
  sq = wq[0] + wq[1] + wq[2] + wq[3];
  const float mu = s * (1.0f / 1024.0f);
  const float rstd = rsqrtf(sq * (1.0f / 1024.0f) - mu * mu + 1e-5f);
  float4 gg = *(const float4*)(g + tid * 4);
  float4 bb = *(const float4*)(be + tid * 4);
  float y0 = (raw.x - mu) * rstd * gg.x + bb.x;
  float y1 = (raw.y - mu) * rstd * gg.y + bb.y;
  float y2 = (raw.z - mu) * rstd * gg.z + bb.z;
  float y3 = (raw.w - mu) * rstd * gg.w + bb.w;
  uint2 outv;
  outv.x = (u32)f2b(y0) | ((u32)f2b(y1) << 16);
  outv.y = (u32)f2b(y2) | ((u32)f2b(y3) << 16);
  *(uint2*)(h + (size_t)row * 1024u + tid * 4) = outv;
}

// ---------------------------------------------------------------- fused QKV GEMM: [q|k|v] = h * Wcat^T + b
// r16: B (weights) no longer staged through LDS — the r12 kernel's LDS traffic
// was ~123 B/cy/CU (~96% of the 128 B/cy pipe): LDS-BW-bound. B-frags are now
// loaded straight from global (L2-resident, 64 row-blocks of reuse; each instr
// fully utilizes its 64B lines) into registers, prefetched 1 kt ahead via a
// manual 2-step unroll (static reg names). A keeps the proven r12 path:
// reg-staged 2-deep + dbuf LDS + 1 barrier/kt + XOR swizzle. LDS 32->16KB,
// LDS bytes/kt halved. Same bf16 bits, same MFMA order -> bit-identical.
__global__ __launch_bounds__(256, 4) void gemm_qkv(const u16* __restrict__ A, const u16* __restrict__ Wcat,
                                                   const float* __restrict__ bq, const float* __restrict__ bk,
                                                   const float* __restrict__ bv,
                                                   u16* __restrict__ qo, u16* __restrict__ ko, u16* __restrict__ vt){
  __shared__ u16 lA[2][4096];
  const int tid = threadIdx.x;
  const int lane = tid & 63, wv = tid >> 6, l15 = lane & 15, quad = lane >> 4;
  const int wr = wv >> 1, wc = wv & 1;
  const int row0 = blockIdx.x * 128, col0 = blockIdx.y * 128;
  const int K = 1024;

  const int r0_ = tid >> 2,         c0_ = tid & 3;
  const int r1_ = (256 + tid) >> 2, c1_ = (256 + tid) & 3;
  const u16* Asrc0 = A + (size_t)(row0 + r0_) * K + (c0_ ^ ((r0_ >> 1) & 3)) * 8;
  const u16* Asrc1 = A + (size_t)(row0 + r1_) * K + (c1_ ^ ((r1_ >> 1) & 3)) * 8;
  const int cr = (quad ^ ((l15 >> 1) & 3)) * 8;
  // direct global B-frag base: frag j of K-tile kt at Bf + j*16*1024 + kt*32
  const u16* Bf = Wcat + (size_t)(col0 + wc * 64 + l15) * 1024u + quad * 8;

  f32x4 acc[4][4] = {};
  uint4 ar0, ar1;
  bf16x8 bc0, bc1, bc2, bc3, bn0, bn1, bn2, bn3;

  // prologue: A tile0 -> LDS buf0 (via regs), A tile1 -> regs, B frags(kt=0) -> regs
  ar0 = *(const uint4*)(Asrc0);
  ar1 = *(const uint4*)(Asrc1);
  *(uint4*)&lA[0][tid * 8] = ar0;
  *(uint4*)&lA[0][(256 + tid) * 8] = ar1;
  ar0 = *(const uint4*)(Asrc0 + 32);
  ar1 = *(const uint4*)(Asrc1 + 32);
  bc0 = *(const bf16x8*)(Bf);
  bc1 = *(const bf16x8*)(Bf + 16384);
  bc2 = *(const bf16x8*)(Bf + 32768);
  bc3 = *(const bf16x8*)(Bf + 49152);
  __syncthreads();

#define QKV_BODY(KT, C0, C1, C2, C3, N0, N1, N2, N3) { \
    const int cur = (KT) & 1; \
    if ((KT) < 31){ \
      *(uint4*)&lA[cur ^ 1][tid * 8] = ar0; \
      *(uint4*)&lA[cur ^ 1][(256 + tid) * 8] = ar1; \
    } \
    if ((KT) < 30){ \
      ar0 = *(const uint4*)(Asrc0 + ((KT) + 2) * 32); \
      ar1 = *(const uint4*)(Asrc1 + ((KT) + 2) * 32); \
    } \
    if ((KT) < 31){ \
      N0 = *(const bf16x8*)(Bf +         ((KT) + 1) * 32); \
      N1 = *(const bf16x8*)(Bf + 16384 + ((KT) + 1) * 32); \
      N2 = *(const bf16x8*)(Bf + 32768 + ((KT) + 1) * 32); \
      N3 = *(const bf16x8*)(Bf + 49152 + ((KT) + 1) * 32); \
    } \
    bf16x8 af[4]; \
    _Pragma("unroll") \
    for (int i = 0; i < 4; ++i) af[i] = *(const bf16x8*)&lA[cur][(wr * 64 + i * 16 + l15) * 32 + cr]; \
    _Pragma("unroll") \
    for (int i = 0; i < 4; ++i){ \
      acc[i][0] = __builtin_amdgcn_mfma_f32_16x16x32_bf16(af[i], C0, acc[i][0], 0, 0, 0); \
      acc[i][1] = __builtin_amdgcn_mfma_f32_16x16x32_bf16(af[i], C1, acc[i][1], 0, 0, 0); \
      acc[i][2] = __builtin_amdgcn_mfma_f32_16x16x32_bf16(af[i], C2, acc[i][2], 0, 0, 0); \
      acc[i][3] = __builtin_amdgcn_mfma_f32_16x16x32_bf16(af[i], C3, acc[i][3], 0, 0, 0); \
    } \
    __syncthreads(); \
  }

  for (int kt2 = 0; kt2 < 32; kt2 += 2){
    QKV_BODY(kt2,     bc0, bc1, bc2, bc3, bn0, bn1, bn2, bn3);
    QKV_BODY(kt2 + 1, bn0, bn1, bn2, bn3, bc0, bc1, bc2, bc3);
  }
#undef QKV_BODY

  const int sel = col0 >> 10;
  if (sel < 2){
    const float* bias = (sel == 0) ? bq : bk;
    u16* dst = (sel == 0) ? qo : ko;
    #pragma unroll
    for (int i = 0; i < 4; ++i){
      const int grow = row0 + wr * 64 + i * 16 + quad * 4;
      #pragma unroll
      for (int j = 0; j < 4; ++j){
        const int gcol = (col0 & 1023) + wc * 64 + j * 16 + l15;
        const float bb = bias[gcol];
        #pragma unroll
        for (int r = 0; r < 4; ++r){
          size_t off = (size_t)(grow + r) * 1024u + gcol;
          dst[off] = f2b(acc[i][j][r] + bb);
        }
      }
    }
  } else {
    // V: transpose through wave-private LDS, write Vt[(b*16+head)*64+d][s]
    // as one full 64B line per d-row per pass.
    u16* pw = &lA[0][0] + wv * 2048;          // [64 d][32 s] u16, 8B-unit XOR u^=d&7
    const int bglob = row0 >> 11;
    const int head  = ((col0 & 1023) >> 6) + wc;
    const int srem0 = (row0 & 2047) + wr * 64;
    const size_t vbase = (size_t)((bglob * 16 + head) * 64) * 2048u;
    #pragma unroll
    for (int p = 0; p < 2; ++p){
      #pragma unroll
      for (int i2 = 0; i2 < 2; ++i2){
        const int i = p * 2 + i2;
        #pragma unroll
        for (int j = 0; j < 4; ++j){
          const int d = j * 16 + l15;
          const float bv_ = bv[(col0 & 1023) + wc * 64 + d];
          const int u = (i2 * 4 + quad) ^ (d & 7);
          uint2 pk;
          pk.x = (u32)f2b(acc[i][j][0] + bv_) | ((u32)f2b(acc[i][j][1] + bv_) << 16);
          pk.y = (u32)f2b(acc[i][j][2] + bv_) | ((u32)f2b(acc[i][j][3] + bv_) << 16);
          *(uint2*)&pw[d * 32 + u * 4] = pk;
        }
      }
      const int dl = lane;
      #pragma unroll
      for (int c = 0; c < 4; ++c){
        const int u0 = (2 * c) ^ (dl & 7), u1 = (2 * c + 1) ^ (dl & 7);
        uint2 lo = *(const uint2*)&pw[dl * 32 + u0 * 4];
        uint2 hi = *(const uint2*)&pw[dl * 32 + u1 * 4];
        uint4 o4; o4.x = lo.x; o4.y = lo.y; o4.z = hi.x; o4.w = hi.y;
        *(uint4*)(vt + vbase + (size_t)dl * 2048u + srem0 + p * 32 + c * 8) = o4;
      }
    }
  }
}

// ---------------------------------------------------------------- GEMM: C = A * W^T + bias + res, fp32 out
// r16: same B-from-global change as gemm_qkv (Wo is 2MB, L2-golden).
__global__ __launch_bounds__(256, 4) void gemm_out(const u16* __restrict__ A, const u16* __restrict__ W,
                                                   const float* __restrict__ bias, const float* __restrict__ res,
                                                   float* __restrict__ C, int M, int N, int K){
  __shared__ u16 lA[2][4096];
  const int tid = threadIdx.x;
  const int lane = tid & 63, wv = tid >> 6, l15 = lane & 15, quad = lane >> 4;
  const int wr = wv >> 1, wc = wv & 1;
  const int row0 = blockIdx.x * 128, col0 = blockIdx.y * 128;

  const int r0_ = tid >> 2,         c0_ = tid & 3;
  const int r1_ = (256 + tid) >> 2, c1_ = (256 + tid) & 3;
  const u16* Asrc0 = A + (size_t)(row0 + r0_) * K + (c0_ ^ ((r0_ >> 1) & 3)) * 8;
  const u16* Asrc1 = A + (size_t)(row0 + r1_) * K + (c1_ ^ ((r1_ >> 1) & 3)) * 8;
  const int cr = (quad ^ ((l15 >> 1) & 3)) * 8;
  const size_t j16K = (size_t)16 * K;
  const u16* Bf = W + (size_t)(col0 + wc * 64 + l15) * K + quad * 8;

  f32x4 acc[4][4] = {};
  const int nkt = K >> 5;
  uint4 ar0, ar1;
  bf16x8 bc0, bc1, bc2, bc3, bn0, bn1, bn2, bn3;

  ar0 = *(const uint4*)(Asrc0);
  ar1 = *(const uint4*)(Asrc1);
  *(uint4*)&lA[0][tid * 8] = ar0;
  *(uint4*)&lA[0][(256 + tid) * 8] = ar1;
  ar0 = *(const uint4*)(Asrc0 + 32);
  ar1 = *(const uint4*)(Asrc1 + 32);
  bc0 = *(const bf16x8*)(Bf);
  bc1 = *(const bf16x8*)(Bf + j16K);
  bc2 = *(const bf16x8*)(Bf + 2 * j16K);
  bc3 = *(const bf16x8*)(Bf + 3 * j16K);
  __syncthreads();

#define OUT_BODY(KT, C0, C1, C2, C3, N0, N1, N2, N3) { \
    const int cur = (KT) & 1; \
    if ((KT) < nkt - 1){ \
      *(uint4*)&lA[cur ^ 1][tid * 8] = ar0; \
      *(uint4*)&lA[cur ^ 1][(256 + tid) * 8] = ar1; \
    } \
    if ((KT) < nkt - 2){ \
      ar0 = *(const uint4*)(Asrc0 + ((KT) + 2) * 32); \
      ar1 = *(const uint4*)(Asrc1 + ((KT) + 2) * 32); \
    } \
    if ((KT) < nkt - 1){ \
      N0 = *(const bf16x8*)(Bf +            ((KT) + 1) * 32); \
      N1 = *(const bf16x8*)(Bf + j16K     + ((KT) + 1) * 32); \
      N2 = *(const bf16x8*)(Bf + 2 * j16K + ((KT) + 1) * 32); \
      N3 = *(const bf16x8*)(Bf + 3 * j16K + ((KT) + 1) * 32); \
    } \
    bf16x8 af[4]; \
    _Pragma("unroll") \
    for (int i = 0; i < 4; ++i) af[i] = *(const bf16x8*)&lA[cur][(wr * 64 + i * 16 + l15) * 32 + cr]; \
    _Pragma("unroll") \
    for (int i = 0; i < 4; ++i){ \
      acc[i][0] = __builtin_amdgcn_mfma_f32_16x16x32_bf16(af[i], C0, acc[i][0], 0, 0, 0); \
      acc[i][1] = __builtin_amdgcn_mfma_f32_16x16x32_bf16(af[i], C1, acc[i][1], 0, 0, 0); \
      acc[i][2] = __builtin_amdgcn_mfma_f32_16x16x32_bf16(af[i], C2, acc[i][2], 0, 0, 0); \
      acc[i][3] = __builtin_amdgcn_mfma_f32_16x16x32_bf16(af[i], C3, acc[i][3], 0, 0, 0); \
    } \
    __syncthreads(); \
  }

  for (int kt2 = 0; kt2 < nkt; kt2 += 2){
    OUT_BODY(kt2,     bc0, bc1, bc2, bc3, bn0, bn1, bn2, bn3);
    OUT_BODY(kt2 + 1, bn0, bn1, bn2, bn3, bc0, bc1, bc2, bc3);
  }
#undef OUT_BODY

  #pragma unroll
  for (int i = 0; i < 4; ++i){
    const int grow = row0 + wr * 64 + i * 16 + quad * 4;
    #pragma unroll
    for (int j = 0; j < 4; ++j){
      const int gcol = col0 + wc * 64 + j * 16 + l15;
      const float bb = bias[gcol];
      #pragma unroll
      for (int r = 0; r < 4; ++r){
        size_t off = (size_t)(grow + r) * N + gcol;
        C[off] = acc[i][j][r] + bb + res[off];
      }
    }
  }
}

// ---------------------------------------------------------------- flash attention (bf16 in/out)
// r16 = r12 attn verbatim (best measured: 77.6 µs). 64 q-rows/wave (4 q-groups),
// grid 512, 2 blocks/CU; permlane butterfly P-redistribution; K/V dbuf
// single-barrier loop; both-sides XOR swizzle (0 conflicts); ones-MFMA
// denominator (r15 showed moving it to VALU lengthens the serial chain: −14%).
// No setprio (r14: −4% here, barrier-locked waves).
__global__ __launch_bounds__(256, 2) void attn_kernel(const u16* __restrict__ Q, const u16* __restrict__ K,
                                                      const u16* __restrict__ Vt, u16* __restrict__ O){
  __shared__ u16 kls[2][64 * 64];
  __shared__ u16 vls[2][64 * 64];
  const int tid = threadIdx.x;
  const int lane = tid & 63, wv = tid >> 6, l15 = lane & 15, quad = lane >> 4;
  const int bh = blockIdx.x & 63, qt = blockIdx.x >> 6;
  const int b = bh >> 4, hh = bh & 15;
  const int q0 = qt * 256;
  const u16* Qg = Q + ((size_t)b * 2048u) * 1024u + hh * 64;
  const u16* Kg = K + ((size_t)b * 2048u) * 1024u + hh * 64;
  const u16* Vg = Vt + (size_t)bh * 64u * 2048u;
  u16* Og = O + ((size_t)b * 2048u) * 1024u + hh * 64;

  const int sr = tid >> 3, sc = tid & 7, sr2 = sr + 32;
  const int sx = (sc ^ (sr & 7)) * 8;
  const int c0 = ((quad ^ (l15 & 7))) * 8;

  const float QSCALE = 0.125f * 1.44269504f;
  bf16x8 qf2[4][2];
  #pragma unroll
  for (int g = 0; g < 4; ++g)
    #pragma unroll
    for (int kk = 0; kk < 2; ++kk){
      qf2[g][kk] = *(const bf16x8*)(Qg + (size_t)(q0 + wv * 64 + g * 16 + l15) * 1024u + kk * 32 + quad * 8);
      #pragma unroll
      for (int e = 0; e < 8; ++e) qf2[g][kk][e] = (__bf16)((float)qf2[g][kk][e] * QSCALE);
    }

  bf16x8 ones_f;
  {
    const __bf16 onev = (__bf16)1.0f, zerov = (__bf16)0.0f;
    #pragma unroll
    for (int e = 0; e < 8; ++e) ones_f[e] = (l15 == 0) ? onev : zerov;
  }

  f32x4 o2[4][4] = {};
  f32x4 o_l[4] = {};
  const f32x4 zf = {0.f, 0.f, 0.f, 0.f};

  uint4 kr0, kr1, vr0, vr1;
  kr0 = *(const uint4*)(Kg + (size_t)sr  * 1024u + sc * 8);
  vr0 = *(const uint4*)(Vg + (size_t)sr  * 2048u + sc * 8);
  kr1 = *(const uint4*)(Kg + (size_t)sr2 * 1024u + sc * 8);
  vr1 = *(const uint4*)(Vg + (size_t)sr2 * 2048u + sc * 8);
  *(uint4*)&kls[0][sr  * 64 + sx] = kr0;
  *(uint4*)&vls[0][sr  * 64 + sx] = vr0;
  *(uint4*)&kls[0][sr2 * 64 + sx] = kr1;
  *(uint4*)&vls[0][sr2 * 64 + sx] = vr1;
  kr0 = *(const uint4*)(Kg + (size_t)(64 + sr)  * 1024u + sc * 8);
  vr0 = *(const uint4*)(Vg + (size_t)sr  * 2048u + 64 + sc * 8);
  kr1 = *(const uint4*)(Kg + (size_t)(64 + sr2) * 1024u + sc * 8);
  vr1 = *(const uint4*)(Vg + (size_t)sr2 * 2048u + 64 + sc * 8);
  __syncthreads();

  for (int kt = 0; kt < 32; ++kt){
    const int cur = kt & 1;
    const u16* kb = kls[cur];
    const u16* vb = vls[cur];
    if (kt < 31){
      u16* kw = kls[cur ^ 1];
      u16* vw = vls[cur ^ 1];
      *(uint4*)&kw[sr  * 64 + sx] = kr0;
      *(uint4*)&vw[sr  * 64 + sx] = vr0;
      *(uint4*)&kw[sr2 * 64 + sx] = kr1;
      *(uint4*)&vw[sr2 * 64 + sx] = vr1;
    }
    if (kt < 30){
      const int s0 = (kt + 2) * 64;
      kr0 = *(const uint4*)(Kg + (size_t)(s0 + sr)  * 1024u + sc * 8);
      vr0 = *(const uint4*)(Vg + (size_t)sr  * 2048u + s0 + sc * 8);
      kr1 = *(const uint4*)(Kg + (size_t)(s0 + sr2) * 1024u + sc * 8);
      vr1 = *(const uint4*)(Vg + (size_t)sr2 * 2048u + s0 + sc * 8);
    }

    f32x4 s2[4][4];
    #pragma unroll
    for (int j = 0; j < 4; ++j){
      const int rb = (j * 16 + l15) * 64;
      bf16x8 kfr0 = *(const bf16x8*)&kb[rb + c0];
      bf16x8 kfr1 = *(const bf16x8*)&kb[rb + (c0 ^ 32)];
      #pragma unroll
      for (int g = 0; g < 4; ++g){
        f32x4 a = __builtin_amdgcn_mfma_f32_16x16x32_bf16(kfr0, qf2[g][0], zf, 0, 0, 0);
        s2[g][j] = __builtin_amdgcn_mfma_f32_16x16x32_bf16(kfr1, qf2[g][1], a, 0, 0, 0);
      }
    }

    #pragma unroll
    for (int g = 0; g < 4; ++g)
      #pragma unroll
      for (int j = 0; j < 4; ++j)
        #pragma unroll
        for (int r = 0; r < 4; ++r)
          s2[g][j][r] = __builtin_amdgcn_exp2f(s2[g][j][r]);

    #pragma unroll
    for (int kk = 0; kk < 2; ++kk){
      bf16x8 afr[4];
      #pragma unroll
      for (int g = 0; g < 4; ++g){
        const int j0 = kk * 2, j1 = j0 + 1;
        u32 A0 = pk_bf16_trunc(s2[g][j0][0], s2[g][j0][1]);
        u32 A1 = pk_bf16_trunc(s2[g][j0][2], s2[g][j0][3]);
        u32 B0 = pk_bf16_trunc(s2[g][j1][0], s2[g][j1][1]);
        u32 B1 = pk_bf16_trunc(s2[g][j1][2], s2[g][j1][3]);
        u32x2 r1 = __builtin_amdgcn_permlane32_swap(A0, B0, false, false);
        u32x2 r2 = __builtin_amdgcn_permlane16_swap(r1[0], r1[1], false, false);
        u32x2 r3 = __builtin_amdgcn_permlane32_swap(A1, B1, false, false);
        u32x2 r4 = __builtin_amdgcn_permlane16_swap(r3[0], r3[1], false, false);
        union { uint4 u; bf16x8 v; } cv;
        cv.u.x = r2[0]; cv.u.y = r4[0]; cv.u.z = r2[1]; cv.u.w = r4[1];
        afr[g] = cv.v;
      }
      #pragma unroll
      for (int g = 0; g < 4; ++g)
        o_l[g] = __builtin_amdgcn_mfma_f32_16x16x32_bf16(afr[g], ones_f, o_l[g], 0, 0, 0);
      #pragma unroll
      for (int j2 = 0; j2 < 4; ++j2){
        bf16x8 bfr = *(const bf16x8*)&vb[(j2 * 16 + l15) * 64 + (c0 ^ (kk * 32))];
        #pragma unroll
        for (int g = 0; g < 4; ++g)
          o2[g][j2] = __builtin_amdgcn_mfma_f32_16x16x32_bf16(afr[g], bfr, o2[g][j2], 0, 0, 0);
      }
    }
    __syncthreads();
  }

  #pragma unroll
  for (int g = 0; g < 4; ++g){
    float lr[4];
    #pragma unroll
    for (int r = 0; r < 4; ++r) lr[r] = 1.0f / __shfl(o_l[g][r], quad * 16);
    #pragma unroll
    for (int j2 = 0; j2 < 4; ++j2){
      #pragma unroll
      for (int r = 0; r < 4; ++r){
        const int qrow = q0 + wv * 64 + g * 16 + quad * 4 + r;
        const int d = j2 * 16 + l15;
        Og[(size_t)qrow * 1024u + d] = f2b(o2[g][j2][r] * lr[r]);
      }
    }
  }
}

extern "C" void kernel_launch(void* const* d_in, const int* in_sizes, int n_in,
                              void* d_out, int out_size, void* d_ws, size_t ws_size,
                              hipStream_t stream){
  (void)in_sizes; (void)n_in; (void)out_size; (void)ws_size;
  const float* x   = (const float*)d_in[0];
  const float* Wq  = (const float*)d_in[1];
  const float* bq  = (const float*)d_in[2];
  const float* Wk  = (const float*)d_in[3];
  const float* bk  = (const float*)d_in[4];
  const float* Wv  = (const float*)d_in[5];
  const float* bv  = (const float*)d_in[6];
  const float* Wo  = (const float*)d_in[7];
  const float* bo  = (const float*)d_in[8];
  const float* lng = (const float*)d_in[9];
  const float* lnb = (const float*)d_in[10];
  float* out = (float*)d_out;

  const size_t TE = (size_t)8192 * 1024;
  u16* ws0 = (u16*)d_ws;          // h
  u16* ws1 = ws0 + TE;            // q -> attention out (in place)
  u16* ws2 = ws1 + TE;            // k
  u16* wsw = ws2 + TE;            // bf16 weights: Wq|Wk|Wv|Wo contiguous
  u16* wob = wsw + (size_t)3 * 1024 * 1024;
  u16* vt  = (u16*)d_out;         // Vt (b,h,d,s) bf16 scratch inside d_out

  pre_kernel<<<dim3(12288), 256, 0, stream>>>(x, lng, lnb, ws0, Wq, Wk, Wv, Wo, wsw);
  gemm_qkv<<<dim3(64, 24), 256, 0, stream>>>(ws0, wsw, bq, bk, bv, ws1, ws2, vt);
  attn_kernel<<<dim3(512), 256, 0, stream>>>(ws1, ws2, vt, ws1);
  gemm_out<<<dim3(64, 8), 256, 0, stream>>>(ws1, wob, bo, x, out, 8192, 1024, 1024);
}

// Round 10
// 264.645 us; speedup vs baseline: 1.2236x; 1.2236x over previous
//
#include <hip/hip_runtime.h>

typedef unsigned short u16;
typedef unsigned int   u32;
using bf16x8 = __attribute__((ext_vector_type(8))) __bf16;
using f32x4  = __attribute__((ext_vector_type(4))) float;
using u32x2  = __attribute__((ext_vector_type(2))) unsigned int;

__device__ __forceinline__ u16 f2b(float f){
  union { float f; u32 i; } v; v.f = f;
  u32 r = v.i + 0x7FFFu + ((v.i >> 16) & 1u);
  return (u16)(r >> 16);
}
__device__ __forceinline__ u32 pk_bf16_trunc(float a, float b){
  return __builtin_amdgcn_perm(__float_as_uint(b), __float_as_uint(a), 0x07060302u);
}

// ---------------------------------------------------------------- fused prelude:
// blocks [0,8192): LayerNorm row kernel; blocks [8192,12288): fp32->bf16 weight cvt.
__global__ __launch_bounds__(256) void pre_kernel(const float* __restrict__ x, const float* __restrict__ g,
                                                  const float* __restrict__ be, u16* __restrict__ h,
                                                  const float* __restrict__ s0, const float* __restrict__ s1,
                                                  const float* __restrict__ s2, const float* __restrict__ s3,
                                                  u16* __restrict__ wd){
  const int tid = threadIdx.x;
  if (blockIdx.x >= 8192){
    const int b2 = blockIdx.x - 8192;
    const float* srcs[4] = {s0, s1, s2, s3};
    const float* s = srcs[b2 >> 10];
    u16* dd = wd + (size_t)(b2 >> 10) * (1024u * 1024u);
    const int i = ((b2 & 1023) * 256 + tid) * 4;
    float4 v = *(const float4*)(s + i);
    uint2 o;
    o.x = (u32)f2b(v.x) | ((u32)f2b(v.y) << 16);
    o.y = (u32)f2b(v.z) | ((u32)f2b(v.w) << 16);
    *(uint2*)(dd + i) = o;
    return;
  }
  const int row = blockIdx.x;
  const float* xr = x + (size_t)row * 1024u;
  float4 raw = *(const float4*)(xr + tid * 4);
  float s  = raw.x + raw.y + raw.z + raw.w;
  float sq = raw.x*raw.x + raw.y*raw.y + raw.z*raw.z + raw.w*raw.w;
  #pragma unroll
  for (int m = 1; m < 64; m <<= 1){ s += __shfl_xor(s, m); sq += __shfl_xor(sq, m); }
  __shared__ float ws[4], wq[4];
  if ((tid & 63) == 0){ ws[tid >> 6] = s; wq[tid >> 6] = sq; }
  __syncthreads();
  s  = ws[0] + ws[1] + ws[2] + ws[3];
  sq = wq[0] + wq[1] + wq[2] + wq[3];
  const float mu = s * (1.0f / 1024.0f);
  const float rstd = rsqrtf(sq * (1.0f / 1024.0f) - mu * mu + 1e-5f);
  float4 gg = *(const float4*)(g + tid * 4);
  float4 bb = *(const float4*)(be + tid * 4);
  float y0 = (raw.x - mu) * rstd * gg.x + bb.x;
  float y1 = (raw.y - mu) * rstd * gg.y + bb.y;
  float y2 = (raw.z - mu) * rstd * gg.z + bb.z;
  float y3 = (raw.w - mu) * rstd * gg.w + bb.w;
  uint2 outv;
  outv.x = (u32)f2b(y0) | ((u32)f2b(y1) << 16);
  outv.y = (u32)f2b(y2) | ((u32)f2b(y3) << 16);
  *(uint2*)(h + (size_t)row * 1024u + tid * 4) = outv;
}

// ---------------------------------------------------------------- fused QKV GEMM: [q|k|v] = h * Wcat^T + b
// r17 = r12 verbatim (best measured; r13/r16 rewrites both regressed —
// latency-bound without the 2-deep reg-staged prefetch). Reg-staged prefetch
// 2 K-tiles ahead, dbuf LDS, ONE __syncthreads per kt; r11 XOR swizzle;
// LDS-staged 64B-line Vt epilogue.
__global__ __launch_bounds__(256) void gemm_qkv(const u16* __restrict__ A, const u16* __restrict__ Wcat,
                                                const float* __restrict__ bq, const float* __restrict__ bk,
                                                const float* __restrict__ bv,
                                                u16* __restrict__ qo, u16* __restrict__ ko, u16* __restrict__ vt){
  __shared__ u16 lA[2][4096];
  __shared__ u16 lB[2][4096];
  const int tid = threadIdx.x;
  const int lane = tid & 63, wv = tid >> 6, l15 = lane & 15, quad = lane >> 4;
  const int wr = wv >> 1, wc = wv & 1;
  const int row0 = blockIdx.x * 128, col0 = blockIdx.y * 128;
  const int K = 1024;

  const int r0_ = tid >> 2,         c0_ = tid & 3;
  const int r1_ = (256 + tid) >> 2, c1_ = (256 + tid) & 3;
  const u16* Asrc0 = A    + (size_t)(row0 + r0_) * K + (c0_ ^ ((r0_ >> 1) & 3)) * 8;
  const u16* Asrc1 = A    + (size_t)(row0 + r1_) * K + (c1_ ^ ((r1_ >> 1) & 3)) * 8;
  const u16* Bsrc0 = Wcat + (size_t)(col0 + r0_) * K + (c0_ ^ ((r0_ >> 1) & 3)) * 8;
  const u16* Bsrc1 = Wcat + (size_t)(col0 + r1_) * K + (c1_ ^ ((r1_ >> 1) & 3)) * 8;
  const int cr = (quad ^ ((l15 >> 1) & 3)) * 8;

  f32x4 acc[4][4] = {};
  uint4 ar0, ar1, br0, br1;
  ar0 = *(const uint4*)(Asrc0);
  ar1 = *(const uint4*)(Asrc1);
  br0 = *(const uint4*)(Bsrc0);
  br1 = *(const uint4*)(Bsrc1);
  *(uint4*)&lA[0][tid * 8] = ar0;
  *(uint4*)&lA[0][(256 + tid) * 8] = ar1;
  *(uint4*)&lB[0][tid * 8] = br0;
  *(uint4*)&lB[0][(256 + tid) * 8] = br1;
  ar0 = *(const uint4*)(Asrc0 + 32);
  ar1 = *(const uint4*)(Asrc1 + 32);
  br0 = *(const uint4*)(Bsrc0 + 32);
  br1 = *(const uint4*)(Bsrc1 + 32);
  __syncthreads();

  for (int kt = 0; kt < 32; ++kt){
    const int cur = kt & 1;
    if (kt < 31){
      *(uint4*)&lA[cur ^ 1][tid * 8] = ar0;
      *(uint4*)&lA[cur ^ 1][(256 + tid) * 8] = ar1;
      *(uint4*)&lB[cur ^ 1][tid * 8] = br0;
      *(uint4*)&lB[cur ^ 1][(256 + tid) * 8] = br1;
    }
    if (kt < 30){
      const int o = (kt + 2) * 32;
      ar0 = *(const uint4*)(Asrc0 + o);
      ar1 = *(const uint4*)(Asrc1 + o);
      br0 = *(const uint4*)(Bsrc0 + o);
      br1 = *(const uint4*)(Bsrc1 + o);
    }
    bf16x8 af[4], bf[4];
    #pragma unroll
    for (int i = 0; i < 4; ++i) af[i] = *(const bf16x8*)&lA[cur][(wr * 64 + i * 16 + l15) * 32 + cr];
    #pragma unroll
    for (int j = 0; j < 4; ++j) bf[j] = *(const bf16x8*)&lB[cur][(wc * 64 + j * 16 + l15) * 32 + cr];
    #pragma unroll
    for (int i = 0; i < 4; ++i)
      #pragma unroll
      for (int j = 0; j < 4; ++j)
        acc[i][j] = __builtin_amdgcn_mfma_f32_16x16x32_bf16(af[i], bf[j], acc[i][j], 0, 0, 0);
    __syncthreads();
  }
  const int sel = col0 >> 10;
  if (sel < 2){
    const float* bias = (sel == 0) ? bq : bk;
    u16* dst = (sel == 0) ? qo : ko;
    #pragma unroll
    for (int i = 0; i < 4; ++i){
      const int grow = row0 + wr * 64 + i * 16 + quad * 4;
      #pragma unroll
      for (int j = 0; j < 4; ++j){
        const int gcol = (col0 & 1023) + wc * 64 + j * 16 + l15;
        const float bb = bias[gcol];
        #pragma unroll
        for (int r = 0; r < 4; ++r){
          size_t off = (size_t)(grow + r) * 1024u + gcol;
          dst[off] = f2b(acc[i][j][r] + bb);
        }
      }
    }
  } else {
    // V: transpose through wave-private LDS, write Vt[(b*16+head)*64+d][s]
    // as one full 64B line per d-row per pass.
    u16* pw = &lA[0][0] + wv * 2048;          // [64 d][32 s] u16, 8B-unit XOR u^=d&7
    const int bglob = row0 >> 11;
    const int head  = ((col0 & 1023) >> 6) + wc;
    const int srem0 = (row0 & 2047) + wr * 64;
    const size_t vbase = (size_t)((bglob * 16 + head) * 64) * 2048u;
    #pragma unroll
    for (int p = 0; p < 2; ++p){
      #pragma unroll
      for (int i2 = 0; i2 < 2; ++i2){
        const int i = p * 2 + i2;
        #pragma unroll
        for (int j = 0; j < 4; ++j){
          const int d = j * 16 + l15;
          const float bv_ = bv[(col0 & 1023) + wc * 64 + d];
          const int u = (i2 * 4 + quad) ^ (d & 7);
          uint2 pk;
          pk.x = (u32)f2b(acc[i][j][0] + bv_) | ((u32)f2b(acc[i][j][1] + bv_) << 16);
          pk.y = (u32)f2b(acc[i][j][2] + bv_) | ((u32)f2b(acc[i][j][3] + bv_) << 16);
          *(uint2*)&pw[d * 32 + u * 4] = pk;
        }
      }
      const int dl = lane;
      #pragma unroll
      for (int c = 0; c < 4; ++c){
        const int u0 = (2 * c) ^ (dl & 7), u1 = (2 * c + 1) ^ (dl & 7);
        uint2 lo = *(const uint2*)&pw[dl * 32 + u0 * 4];
        uint2 hi = *(const uint2*)&pw[dl * 32 + u1 * 4];
        uint4 o4; o4.x = lo.x; o4.y = lo.y; o4.z = hi.x; o4.w = hi.y;
        *(uint4*)(vt + vbase + (size_t)dl * 2048u + srem0 + p * 32 + c * 8) = o4;
      }
    }
  }
}

// ---------------------------------------------------------------- GEMM: C = A * W^T + bias + res, fp32 out
// r17 = r12 verbatim.
__global__ __launch_bounds__(256) void gemm_out(const u16* __restrict__ A, const u16* __restrict__ W,
                                                const float* __restrict__ bias, const float* __restrict__ res,
                                                float* __restrict__ C, int M, int N, int K){
  __shared__ u16 lA[2][4096];
  __shared__ u16 lB[2][4096];
  const int tid = threadIdx.x;
  const int lane = tid & 63, wv = tid >> 6, l15 = lane & 15, quad = lane >> 4;
  const int wr = wv >> 1, wc = wv & 1;
  const int row0 = blockIdx.x * 128, col0 = blockIdx.y * 128;

  const int r0_ = tid >> 2,         c0_ = tid & 3;
  const int r1_ = (256 + tid) >> 2, c1_ = (256 + tid) & 3;
  const u16* Asrc0 = A + (size_t)(row0 + r0_) * K + (c0_ ^ ((r0_ >> 1) & 3)) * 8;
  const u16* Asrc1 = A + (size_t)(row0 + r1_) * K + (c1_ ^ ((r1_ >> 1) & 3)) * 8;
  const u16* Bsrc0 = W + (size_t)(col0 + r0_) * K + (c0_ ^ ((r0_ >> 1) & 3)) * 8;
  const u16* Bsrc1 = W + (size_t)(col0 + r1_) * K + (c1_ ^ ((r1_ >> 1) & 3)) * 8;
  const int cr = (quad ^ ((l15 >> 1) & 3)) * 8;

  f32x4 acc[4][4] = {};
  const int nkt = K >> 5;
  uint4 ar0, ar1, br0, br1;
  ar0 = *(const uint4*)(Asrc0);
  ar1 = *(const uint4*)(Asrc1);
  br0 = *(const uint4*)(Bsrc0);
  br1 = *(const uint4*)(Bsrc1);
  *(uint4*)&lA[0][tid * 8] = ar0;
  *(uint4*)&lA[0][(256 + tid) * 8] = ar1;
  *(uint4*)&lB[0][tid * 8] = br0;
  *(uint4*)&lB[0][(256 + tid) * 8] = br1;
  ar0 = *(const uint4*)(Asrc0 + 32);
  ar1 = *(const uint4*)(Asrc1 + 32);
  br0 = *(const uint4*)(Bsrc0 + 32);
  br1 = *(const uint4*)(Bsrc1 + 32);
  __syncthreads();

  for (int kt = 0; kt < nkt; ++kt){
    const int cur = kt & 1;
    if (kt < nkt - 1){
      *(uint4*)&lA[cur ^ 1][tid * 8] = ar0;
      *(uint4*)&lA[cur ^ 1][(256 + tid) * 8] = ar1;
      *(uint4*)&lB[cur ^ 1][tid * 8] = br0;
      *(uint4*)&lB[cur ^ 1][(256 + tid) * 8] = br1;
    }
    if (kt < nkt - 2){
      const int o = (kt + 2) * 32;
      ar0 = *(const uint4*)(Asrc0 + o);
      ar1 = *(const uint4*)(Asrc1 + o);
      br0 = *(const uint4*)(Bsrc0 + o);
      br1 = *(const uint4*)(Bsrc1 + o);
    }
    bf16x8 af[4], bf[4];
    #pragma unroll
    for (int i = 0; i < 4; ++i) af[i] = *(const bf16x8*)&lA[cur][(wr * 64 + i * 16 + l15) * 32 + cr];
    #pragma unroll
    for (int j = 0; j < 4; ++j) bf[j] = *(const bf16x8*)&lB[cur][(wc * 64 + j * 16 + l15) * 32 + cr];
    #pragma unroll
    for (int i = 0; i < 4; ++i)
      #pragma unroll
      for (int j = 0; j < 4; ++j)
        acc[i][j] = __builtin_amdgcn_mfma_f32_16x16x32_bf16(af[i], bf[j], acc[i][j], 0, 0, 0);
    __syncthreads();
  }
  #pragma unroll
  for (int i = 0; i < 4; ++i){
    const int grow = row0 + wr * 64 + i * 16 + quad * 4;
    #pragma unroll
    for (int j = 0; j < 4; ++j){
      const int gcol = col0 + wc * 64 + j * 16 + l15;
      const float bb = bias[gcol];
      #pragma unroll
      for (int r = 0; r < 4; ++r){
        size_t off = (size_t)(grow + r) * N + gcol;
        C[off] = acc[i][j][r] + bb + res[off];
      }
    }
  }
}

// ---------------------------------------------------------------- flash attention (bf16 in/out)
// r17 = r12 attn verbatim (best measured: 77.6 µs). 64 q-rows/wave (4 q-groups),
// grid 512, 2 blocks/CU; permlane butterfly P-redistribution; K/V dbuf
// single-barrier loop; both-sides XOR swizzle (0 conflicts); ones-MFMA
// denominator (r15: moving it to VALU = −14%; r14: setprio = −4%).
__global__ __launch_bounds__(256, 2) void attn_kernel(const u16* __restrict__ Q, const u16* __restrict__ K,
                                                      const u16* __restrict__ Vt, u16* __restrict__ O){
  __shared__ u16 kls[2][64 * 64];
  __shared__ u16 vls[2][64 * 64];
  const int tid = threadIdx.x;
  const int lane = tid & 63, wv = tid >> 6, l15 = lane & 15, quad = lane >> 4;
  const int bh = blockIdx.x & 63, qt = blockIdx.x >> 6;
  const int b = bh >> 4, hh = bh & 15;
  const int q0 = qt * 256;
  const u16* Qg = Q + ((size_t)b * 2048u) * 1024u + hh * 64;
  const u16* Kg = K + ((size_t)b * 2048u) * 1024u + hh * 64;
  const u16* Vg = Vt + (size_t)bh * 64u * 2048u;
  u16* Og = O + ((size_t)b * 2048u) * 1024u + hh * 64;

  const int sr = tid >> 3, sc = tid & 7, sr2 = sr + 32;
  const int sx = (sc ^ (sr & 7)) * 8;
  const int c0 = ((quad ^ (l15 & 7))) * 8;

  const float QSCALE = 0.125f * 1.44269504f;
  bf16x8 qf2[4][2];
  #pragma unroll
  for (int g = 0; g < 4; ++g)
    #pragma unroll
    for (int kk = 0; kk < 2; ++kk){
      qf2[g][kk] = *(const bf16x8*)(Qg + (size_t)(q0 + wv * 64 + g * 16 + l15) * 1024u + kk * 32 + quad * 8);
      #pragma unroll
      for (int e = 0; e < 8; ++e) qf2[g][kk][e] = (__bf16)((float)qf2[g][kk][e] * QSCALE);
    }

  bf16x8 ones_f;
  {
    const __bf16 onev = (__bf16)1.0f, zerov = (__bf16)0.0f;
    #pragma unroll
    for (int e = 0; e < 8; ++e) ones_f[e] = (l15 == 0) ? onev : zerov;
  }

  f32x4 o2[4][4] = {};
  f32x4 o_l[4] = {};
  const f32x4 zf = {0.f, 0.f, 0.f, 0.f};

  uint4 kr0, kr1, vr0, vr1;
  kr0 = *(const uint4*)(Kg + (size_t)sr  * 1024u + sc * 8);
  vr0 = *(const uint4*)(Vg + (size_t)sr  * 2048u + sc * 8);
  kr1 = *(const uint4*)(Kg + (size_t)sr2 * 1024u + sc * 8);
  vr1 = *(const uint4*)(Vg + (size_t)sr2 * 2048u + sc * 8);
  *(uint4*)&kls[0][sr  * 64 + sx] = kr0;
  *(uint4*)&vls[0][sr  * 64 + sx] = vr0;
  *(uint4*)&kls[0][sr2 * 64 + sx] = kr1;
  *(uint4*)&vls[0][sr2 * 64 + sx] = vr1;
  kr0 = *(const uint4*)(Kg + (size_t)(64 + sr)  * 1024u + sc * 8);
  vr0 = *(const uint4*)(Vg + (size_t)sr  * 2048u + 64 + sc * 8);
  kr1 = *(const uint4*)(Kg + (size_t)(64 + sr2) * 1024u + sc * 8);
  vr1 = *(const uint4*)(Vg + (size_t)sr2 * 2048u + 64 + sc * 8);
  __syncthreads();

  for (int kt = 0; kt < 32; ++kt){
    const int cur = kt & 1;
    const u16* kb = kls[cur];
    const u16* vb = vls[cur];
    if (kt < 31){
      u16* kw = kls[cur ^ 1];
      u16* vw = vls[cur ^ 1];
      *(uint4*)&kw[sr  * 64 + sx] = kr0;
      *(uint4*)&vw[sr  * 64 + sx] = vr0;
      *(uint4*)&kw[sr2 * 64 + sx] = kr1;
      *(uint4*)&vw[sr2 * 64 + sx] = vr1;
    }
    if (kt < 30){
      const int s0 = (kt + 2) * 64;
      kr0 = *(const uint4*)(Kg + (size_t)(s0 + sr)  * 1024u + sc * 8);
      vr0 = *(const uint4*)(Vg + (size_t)sr  * 2048u + s0 + sc * 8);
      kr1 = *(const uint4*)(Kg + (size_t)(s0 + sr2) * 1024u + sc * 8);
      vr1 = *(const uint4*)(Vg + (size_t)sr2 * 2048u + s0 + sc * 8);
    }

    f32x4 s2[4][4];
    #pragma unroll
    for (int j = 0; j < 4; ++j){
      const int rb = (j * 16 + l15) * 64;
      bf16x8 kfr0 = *(const bf16x8*)&kb[rb + c0];
      bf16x8 kfr1 = *(const bf16x8*)&kb[rb + (c0 ^ 32)];
      #pragma unroll
      for (int g = 0; g < 4; ++g){
        f32x4 a = __builtin_amdgcn_mfma_f32_16x16x32_bf16(kfr0, qf2[g][0], zf, 0, 0, 0);
        s2[g][j] = __builtin_amdgcn_mfma_f32_16x16x32_bf16(kfr1, qf2[g][1], a, 0, 0, 0);
      }
    }

    #pragma unroll
    for (int g = 0; g < 4; ++g)
      #pragma unroll
      for (int j = 0; j < 4; ++j)
        #pragma unroll
        for (int r = 0; r < 4; ++r)
          s2[g][j][r] = __builtin_amdgcn_exp2f(s2[g][j][r]);

    #pragma unroll
    for (int kk = 0; kk < 2; ++kk){
      bf16x8 afr[4];
      #pragma unroll
      for (int g = 0; g < 4; ++g){
        const int j0 = kk * 2, j1 = j0 + 1;
        u32 A0 = pk_bf16_trunc(s2[g][j0][0], s2[g][j0][1]);
        u32 A1 = pk_bf16_trunc(s2[g][j0][2], s2[g][j0][3]);
        u32 B0 = pk_bf16_trunc(s2[g][j1][0], s2[g][j1][1]);
        u32 B1 = pk_bf16_trunc(s2[g][j1][2], s2[g][j1][3]);
        u32x2 r1 = __builtin_amdgcn_permlane32_swap(A0, B0, false, false);
        u32x2 r2 = __builtin_amdgcn_permlane16_swap(r1[0], r1[1], false, false);
        u32x2 r3 = __builtin_amdgcn_permlane32_swap(A1, B1, false, false);
        u32x2 r4 = __builtin_amdgcn_permlane16_swap(r3[0], r3[1], false, false);
        union { uint4 u; bf16x8 v; } cv;
        cv.u.x = r2[0]; cv.u.y = r4[0]; cv.u.z = r2[1]; cv.u.w = r4[1];
        afr[g] = cv.v;
      }
      #pragma unroll
      for (int g = 0; g < 4; ++g)
        o_l[g] = __builtin_amdgcn_mfma_f32_16x16x32_bf16(afr[g], ones_f, o_l[g], 0, 0, 0);
      #pragma unroll
      for (int j2 = 0; j2 < 4; ++j2){
        bf16x8 bfr = *(const bf16x8*)&vb[(j2 * 16 + l15) * 64 + (c0 ^ (kk * 32))];
        #pragma unroll
        for (int g = 0; g < 4; ++g)
          o2[g][j2] = __builtin_amdgcn_mfma_f32_16x16x32_bf16(afr[g], bfr, o2[g][j2], 0, 0, 0);
      }
    }
    __syncthreads();
  }

  #pragma unroll
  for (int g = 0; g < 4; ++g){
    float lr[4];
    #pragma unroll
    for (int r = 0; r < 4; ++r) lr[r] = 1.0f / __shfl(o_l[g][r], quad * 16);
    #pragma unroll
    for (int j2 = 0; j2 < 4; ++j2){
      #pragma unroll
      for (int r = 0; r < 4; ++r){
        const int qrow = q0 + wv * 64 + g * 16 + quad * 4 + r;
        const int d = j2 * 16 + l15;
        Og[(size_t)qrow * 1024u + d] = f2b(o2[g][j2][r] * lr[r]);
      }
    }
  }
}

extern "C" void kernel_launch(void* const* d_in, const int* in_sizes, int n_in,
                              void* d_out, int out_size, void* d_ws, size_t ws_size,
                              hipStream_t stream){
  (void)in_sizes; (void)n_in; (void)out_size; (void)ws_size;
  const float* x   = (const float*)d_in[0];
  const float* Wq  = (const float*)d_in[1];
  const float* bq  = (const float*)d_in[2];
  const float* Wk  = (const float*)d_in[3];
  const float* bk  = (const float*)d_in[4];
  const float* Wv  = (const float*)d_in[5];
  const float* bv  = (const float*)d_in[6];
  const float* Wo  = (const float*)d_in[7];
  const float* bo  = (const float*)d_in[8];
  const float* lng = (const float*)d_in[9];
  const float* lnb = (const float*)d_in[10];
  float* out = (float*)d_out;

  const size_t TE = (size_t)8192 * 1024;
  u16* ws0 = (u16*)d_ws;          // h
  u16* ws1 = ws0 + TE;            // q -> attention out (in place)
  u16* ws2 = ws1 + TE;            // k
  u16* wsw = ws2 + TE;            // bf16 weights: Wq|Wk|Wv|Wo contiguous
  u16* wob = wsw + (size_t)3 * 1024 * 1024;
  u16* vt  = (u16*)d_out;         // Vt (b,h,d,s) bf16 scratch inside d_out

  pre_kernel<<<dim3(12288), 256, 0, stream>>>(x, lng, lnb, ws0, Wq, Wk, Wv, Wo, wsw);
  gemm_qkv<<<dim3(64, 24), 256, 0, stream>>>(ws0, wsw, bq, bk, bv, ws1, ws2, vt);
  attn_kernel<<<dim3(512), 256, 0, stream>>>(ws1, ws2, vt, ws1);
  gemm_out<<<dim3(64, 8), 256, 0, stream>>>(ws1, wob, bo, x, out, 8192, 1024, 1024);
}